// Round 10
// baseline (688.290 us; speedup 1.0000x reference)
//
#include <hip/hip_runtime.h>

// Problem constants: B=4, T=2048, C=1024, H=16, HD=64
#define TT 2048
#define CC 1024
#define HH 16
#define HD 64

typedef __bf16 bf16x8 __attribute__((ext_vector_type(8)));
typedef float f32x4 __attribute__((ext_vector_type(4)));

using as1_cvoid = __attribute__((address_space(1))) const void;
using as3_void  = __attribute__((address_space(3))) void;

__device__ __forceinline__ unsigned short f2bf(float f) {
  __bf16 b = (__bf16)f;
  return __builtin_bit_cast(unsigned short, b);
}

__device__ __forceinline__ void gload_lds16(const void* g, void* l) {
  __builtin_amdgcn_global_load_lds((as1_cvoid*)g, (as3_void*)l, 16, 0, 0);
}

// ---------------- cast f32 -> bf16 ----------------
__global__ void castk(const float* __restrict__ s, unsigned short* __restrict__ d, int n) {
  int i = (blockIdx.x * blockDim.x + threadIdx.x) * 4;
  if (i < n) {
    float4 v = *reinterpret_cast<const float4*>(s + i);
    ushort4 o;
    o.x = f2bf(v.x); o.y = f2bf(v.y); o.z = f2bf(v.z); o.w = f2bf(v.w);
    *reinterpret_cast<ushort4*>(d + i) = o;
  }
}

// ---------------- GEMM: C[M,N] = A[M,K] @ B[N,K]^T (verified) ----------------
#define BM 128
#define BN 128
#define BK 64

__device__ __forceinline__ void stage128x64(const unsigned short* __restrict__ src,
                                            int ld, char* ldsbase, int tid) {
#pragma unroll
  for (int it = 0; it < 4; ++it) {
    int j = it * 256 + tid;          // 16B block index, 1024 total
    int row = j >> 3;                // 8 blocks per 128B row
    int lg = (j & 7) ^ (row & 7);    // swizzled k-group (pre-swizzle SOURCE)
    const unsigned short* g = src + row * ld + lg * 8;
    gload_lds16(g, ldsbase + j * 16);
  }
}

template <int OUTF32>
__global__ __launch_bounds__(256)
void gemm_bt(const unsigned short* __restrict__ A, const unsigned short* __restrict__ B,
             void* __restrict__ Cout, int M, int N, int K) {
  __shared__ char lds[2][2 * BM * BK * 2];  // [buf][A 16KB | B 16KB]
  const int tid = threadIdx.x;
  const int lane = tid & 63;
  const int w = tid >> 6;
  const int wr = w >> 1, wc = w & 1;
  const int l15 = lane & 15, l4 = lane >> 4;

  const int rowA0 = blockIdx.x * BM;
  const int colB0 = blockIdx.y * BN;

  f32x4 acc[4][4] = {};

  const unsigned short* Abase = A + (size_t)rowA0 * K;
  const unsigned short* Bbase = B + (size_t)colB0 * K;

  int a_off[2][4], b_off[2][4];
#pragma unroll
  for (int kk = 0; kk < 2; ++kk)
#pragma unroll
    for (int m = 0; m < 4; ++m) {
      int row = wr * 64 + m * 16 + l15;
      int g = kk * 4 + l4;
      a_off[kk][m] = row * 128 + ((g ^ (row & 7)) * 16);
      int rowb = wc * 64 + m * 16 + l15;
      b_off[kk][m] = rowb * 128 + ((g ^ (rowb & 7)) * 16);
    }

  const int NT = K / BK;
  stage128x64(Abase, K, &lds[0][0], tid);
  stage128x64(Bbase, K, &lds[0][BM * BK * 2], tid);
  asm volatile("s_waitcnt vmcnt(0)" ::: "memory");
  __syncthreads();

  int buf = 0;
  for (int t = 0; t < NT; ++t) {
    if (t + 1 < NT) {
      stage128x64(Abase + (t + 1) * BK, K, &lds[buf ^ 1][0], tid);
      stage128x64(Bbase + (t + 1) * BK, K, &lds[buf ^ 1][BM * BK * 2], tid);
    }
    const char* aLds = &lds[buf][0];
    const char* bLds = &lds[buf][BM * BK * 2];
#pragma unroll
    for (int kk = 0; kk < 2; ++kk) {
      bf16x8 af[4], bfv[4];
#pragma unroll
      for (int m = 0; m < 4; ++m) af[m] = *reinterpret_cast<const bf16x8*>(aLds + a_off[kk][m]);
#pragma unroll
      for (int n = 0; n < 4; ++n) bfv[n] = *reinterpret_cast<const bf16x8*>(bLds + b_off[kk][n]);
#pragma unroll
      for (int m = 0; m < 4; ++m)
#pragma unroll
        for (int n = 0; n < 4; ++n)
          acc[m][n] = __builtin_amdgcn_mfma_f32_16x16x32_bf16(af[m], bfv[n], acc[m][n], 0, 0, 0);
    }
    asm volatile("s_waitcnt vmcnt(0)" ::: "memory");
    __syncthreads();
    buf ^= 1;
  }

#pragma unroll
  for (int m = 0; m < 4; ++m) {
#pragma unroll
    for (int r = 0; r < 4; ++r) {
      int row = rowA0 + wr * 64 + m * 16 + l4 * 4 + r;
#pragma unroll
      for (int n = 0; n < 4; ++n) {
        int col = colB0 + wc * 64 + n * 16 + l15;
        if (OUTF32)
          reinterpret_cast<float*>(Cout)[(size_t)row * N + col] = acc[m][n][r];
        else
          reinterpret_cast<unsigned short*>(Cout)[(size_t)row * N + col] = f2bf(acc[m][n][r]);
      }
    }
  }
}

// ---------------- causal flash attention ----------------
// Round-9 (verified PASS) dataflow + two deltas:
//  1) pipelined staging: K double-buffered in LDS, K(t+1) gload + V(t+1)
//     reg-load issued BEFORE compute(t); vmcnt(0) moved to after compute ->
//     HBM latency hidden under the tile body. Only ONE global_load_lds dest
//     region per section (avoids the round-4/7 poison pattern).
//  2) log2-space softmax: sc2 = sc*log2(e); m kept in log2 units; saves the
//     *LOG2E multiplies (mathematically equivalent).
__global__ __launch_bounds__(256, 4)
void attn(const unsigned short* __restrict__ Q, const unsigned short* __restrict__ Kmat,
          const unsigned short* __restrict__ V, unsigned short* __restrict__ O) {
  __shared__ char smem[32768];  // Ks0 8KB | Ks1 8KB | VsL 8KB | Pw 4x2KB
  const int tid = threadIdx.x, lane = tid & 63, w = tid >> 6;
  const int l15 = lane & 15, l4 = lane >> 4;
  const int i = blockIdx.x;             // [0, 16): pair index
  const int bh = blockIdx.y;
  const int b = bh >> 4, h = bh & 15;
  const size_t bT = (size_t)b * TT;
  const int q0A = i * 64 + w * 16;          // group A: qblock i
  const int q0B = (31 - i) * 64 + w * 16;   // group B: qblock 31-i
  const int lastA = i;                      // A's diagonal tile
  const int lastB = 31 - i;                 // B's diagonal tile (= loop bound)

  char* VsL = smem + 16384;
  char* Pw = smem + 24576 + w * 2048;

  // Q fragments (A-operand): row = l15, k = kk*32 + l4*8 + j
  const unsigned short* qpA = Q + (bT + q0A + l15) * CC + h * HD;
  const unsigned short* qpB = Q + (bT + q0B + l15) * CC + h * HD;
  bf16x8 qfA[2], qfB[2];
  qfA[0] = *reinterpret_cast<const bf16x8*>(qpA + l4 * 8);
  qfA[1] = *reinterpret_cast<const bf16x8*>(qpA + 32 + l4 * 8);
  qfB[0] = *reinterpret_cast<const bf16x8*>(qpB + l4 * 8);
  qfB[1] = *reinterpret_cast<const bf16x8*>(qpB + 32 + l4 * 8);

  f32x4 oA[4] = {}, oB[4] = {};
  float mA[4], lA[4], mB[4], lB[4];
#pragma unroll
  for (int r = 0; r < 4; ++r) {
    mA[r] = -1e30f; lA[r] = 0.f; mB[r] = -1e30f; lB[r] = 0.f;
  }

  int koff[4][2], voff[4][2], poff[2];
#pragma unroll
  for (int n = 0; n < 4; ++n)
#pragma unroll
    for (int kk = 0; kk < 2; ++kk) {
      int row = n * 16 + l15;
      int g = kk * 4 + l4;
      koff[n][kk] = row * 128 + ((g ^ (row & 7)) * 16);
      voff[n][kk] = row * 128 + ((g ^ (row & 7) ^ ((row >> 3) & 7)) * 16);
    }
#pragma unroll
  for (int kk = 0; kk < 2; ++kk) {
    int row = l15;
    int g = kk * 4 + l4;
    poff[kk] = row * 128 + ((g ^ (row & 7)) * 16);
  }

  const float sc2 = 0.125f * 1.44269504f;  // HD^-0.5 * log2(e); m in log2 units
  bf16x8 vreg[2];

  // stage K(t) gload into dst; load V(t) into vreg
#define STAGE_K(KB0, DST)                                                        \
  _Pragma("unroll")                                                              \
  for (int it = 0; it < 2; ++it) {                                               \
    int j = it * 256 + tid;                                                      \
    int row = j >> 3;                                                            \
    int lg = (j & 7) ^ (row & 7);                                                \
    gload_lds16(Kmat + (bT + (KB0) + row) * CC + h * HD + lg * 8, (DST) + j * 16); \
  }
#define LOAD_V(KB0)                                                              \
  _Pragma("unroll")                                                              \
  for (int it = 0; it < 2; ++it) {                                               \
    int j = it * 256 + tid;                                                      \
    int key = j >> 3;                                                            \
    int d0 = (j & 7) * 8;                                                        \
    vreg[it] = *reinterpret_cast<const bf16x8*>(V + (bT + (KB0) + key) * CC + h * HD + d0); \
  }
#define WRITE_V()                                                                \
  _Pragma("unroll")                                                              \
  for (int it = 0; it < 2; ++it) {                                               \
    int j = it * 256 + tid;                                                      \
    int key = j >> 3;                                                            \
    int d0 = (j & 7) * 8;                                                        \
    _Pragma("unroll")                                                            \
    for (int jj = 0; jj < 8; ++jj) {                                             \
      int row = d0 + jj;                                                         \
      int gq = key >> 3;                                                         \
      int off = row * 128 + ((gq ^ (row & 7) ^ ((row >> 3) & 7)) * 16) + (key & 7) * 2; \
      *reinterpret_cast<__bf16*>(VsL + off) = vreg[it][jj];                      \
    }                                                                            \
  }

  // verified per-tile body (round-9 math, log2-space softmax)
#define TILE_BODY(QF, OO, MR, LR, Q0, ISDIAG, KB0)                               \
  {                                                                              \
    f32x4 s_[4] = {};                                                            \
    _Pragma("unroll")                                                            \
    for (int n = 0; n < 4; ++n)                                                  \
      _Pragma("unroll")                                                          \
      for (int kk = 0; kk < 2; ++kk) {                                           \
        bf16x8 kf = *reinterpret_cast<const bf16x8*>(Ks + koff[n][kk]);          \
        s_[n] = __builtin_amdgcn_mfma_f32_16x16x32_bf16(QF[kk], kf, s_[n], 0, 0, 0); \
      }                                                                          \
    if (ISDIAG) {                                                                \
      _Pragma("unroll")                                                          \
      for (int n = 0; n < 4; ++n) {                                              \
        int key = (KB0) + n * 16 + l15;                                          \
        _Pragma("unroll")                                                        \
        for (int r = 0; r < 4; ++r) {                                            \
          int q = (Q0) + l4 * 4 + r;                                             \
          if (key > q) s_[n][r] = -1e30f;                                        \
        }                                                                        \
      }                                                                          \
    }                                                                            \
    float tm_[4];                                                                \
    _Pragma("unroll")                                                            \
    for (int r = 0; r < 4; ++r)                                                  \
      tm_[r] = fmaxf(fmaxf(s_[0][r], s_[1][r]), fmaxf(s_[2][r], s_[3][r]));      \
    _Pragma("unroll")                                                            \
    for (int off = 1; off < 16; off <<= 1)                                       \
      _Pragma("unroll")                                                          \
      for (int r = 0; r < 4; ++r) tm_[r] = fmaxf(tm_[r], __shfl_xor(tm_[r], off, 64)); \
    float mnew_[4], alpha_[4];                                                   \
    _Pragma("unroll")                                                            \
    for (int r = 0; r < 4; ++r) {                                                \
      mnew_[r] = fmaxf(MR[r], tm_[r] * sc2);                                     \
      alpha_[r] = exp2f(MR[r] - mnew_[r]);                                       \
      MR[r] = mnew_[r];                                                          \
    }                                                                            \
    float ts_[4] = {0.f, 0.f, 0.f, 0.f};                                         \
    _Pragma("unroll")                                                            \
    for (int n = 0; n < 4; ++n)                                                  \
      _Pragma("unroll")                                                          \
      for (int r = 0; r < 4; ++r) {                                              \
        float p = exp2f(s_[n][r] * sc2 - mnew_[r]);                              \
        s_[n][r] = p;                                                            \
        ts_[r] += p;                                                             \
      }                                                                          \
    _Pragma("unroll")                                                            \
    for (int off = 1; off < 16; off <<= 1)                                       \
      _Pragma("unroll")                                                          \
      for (int r = 0; r < 4; ++r) ts_[r] += __shfl_xor(ts_[r], off, 64);         \
    _Pragma("unroll")                                                            \
    for (int r = 0; r < 4; ++r) LR[r] = LR[r] * alpha_[r] + ts_[r];              \
    _Pragma("unroll")                                                            \
    for (int nf2 = 0; nf2 < 4; ++nf2)                                            \
      _Pragma("unroll")                                                          \
      for (int r = 0; r < 4; ++r) OO[nf2][r] *= alpha_[r];                       \
    _Pragma("unroll")                                                            \
    for (int n = 0; n < 4; ++n)                                                  \
      _Pragma("unroll")                                                          \
      for (int r = 0; r < 4; ++r) {                                              \
        int row = l4 * 4 + r;                                                    \
        int col = n * 16 + l15;                                                  \
        int gq = col >> 3;                                                       \
        int off = row * 128 + ((gq ^ (row & 7)) * 16) + (col & 7) * 2;           \
        *reinterpret_cast<__bf16*>(Pw + off) = (__bf16)s_[n][r];                 \
      }                                                                          \
    asm volatile("s_waitcnt lgkmcnt(0)" ::: "memory");                           \
    __builtin_amdgcn_sched_barrier(0);                                           \
    _Pragma("unroll")                                                            \
    for (int kk = 0; kk < 2; ++kk) {                                             \
      bf16x8 pf = *reinterpret_cast<const bf16x8*>(Pw + poff[kk]);               \
      _Pragma("unroll")                                                          \
      for (int nf2 = 0; nf2 < 4; ++nf2) {                                        \
        bf16x8 vf = *reinterpret_cast<const bf16x8*>(VsL + voff[nf2][kk]);       \
        OO[nf2] = __builtin_amdgcn_mfma_f32_16x16x32_bf16(pf, vf, OO[nf2], 0, 0, 0); \
      }                                                                          \
    }                                                                            \
  }

  // prologue: stage tile 0 (K -> Ks0, V -> regs -> VsL)
  STAGE_K(0, smem)
  LOAD_V(0)
  asm volatile("s_waitcnt vmcnt(0)" ::: "memory");
  WRITE_V()
  __syncthreads();

  int buf = 0;
  for (int t = 0; t <= lastB; ++t) {
    const int kb0 = t * 64;
    // issue next tile's loads BEFORE compute: K(t+1) -> Ks[buf^1] (dead region),
    // V(t+1) -> vreg (free). Latency hides under the tile body.
    if (t < lastB) {
      char* kDst = smem + (buf ^ 1) * 8192;
      STAGE_K(kb0 + 64, kDst)
      LOAD_V(kb0 + 64)
    }
    const char* Ks = smem + buf * 8192;

    if (t <= lastA) {  // wave-uniform guard
      TILE_BODY(qfA, oA, mA, lA, q0A, (t == lastA), kb0)
    }
    TILE_BODY(qfB, oB, mB, lB, q0B, (t == lastB), kb0)

    __syncthreads();  // all waves done reading VsL / Ks[buf] / Pw
    if (t < lastB) {
      asm volatile("s_waitcnt vmcnt(0)" ::: "memory");  // K(t+1), V(t+1) landed
      WRITE_V()
      __syncthreads();  // V(t+1) visible; K(t+1) in Ks[buf^1]
    }
    buf ^= 1;
  }
#undef TILE_BODY
#undef STAGE_K
#undef LOAD_V
#undef WRITE_V

  // epilogue: O[b,q, h*64+d] bf16, both groups
#pragma unroll
  for (int nf2 = 0; nf2 < 4; ++nf2)
#pragma unroll
    for (int r = 0; r < 4; ++r) {
      int col = h * HD + nf2 * 16 + l15;
      int qA = q0A + l4 * 4 + r;
      O[(bT + qA) * CC + col] = f2bf(oA[nf2][r] / lA[r]);
      int qB = q0B + l4 * 4 + r;
      O[(bT + qB) * CC + col] = f2bf(oB[nf2][r] / lB[r]);
    }
}

// ---------------- launch ----------------
extern "C" void kernel_launch(void* const* d_in, const int* in_sizes, int n_in,
                              void* d_out, int out_size, void* d_ws, size_t ws_size,
                              hipStream_t stream) {
  const float* x  = (const float*)d_in[0];
  const float* Wq = (const float*)d_in[1];
  const float* Wk = (const float*)d_in[2];
  const float* Wv = (const float*)d_in[3];
  const float* Wo = (const float*)d_in[4];

  char* ws = (char*)d_ws;
  const size_t NX = (size_t)4 * TT * CC;       // 8388608
  const size_t NW = (size_t)CC * CC;           // 1048576
  unsigned short* xb  = (unsigned short*)(ws);
  unsigned short* qb  = (unsigned short*)(ws + 1 * NX * 2);
  unsigned short* kb  = (unsigned short*)(ws + 2 * NX * 2);
  unsigned short* vb  = (unsigned short*)(ws + 3 * NX * 2);
  unsigned short* ob  = (unsigned short*)(ws + 4 * NX * 2);
  unsigned short* wqb = (unsigned short*)(ws + 5 * NX * 2);
  unsigned short* wkb = (unsigned short*)(ws + 5 * NX * 2 + 1 * NW * 2);
  unsigned short* wvb = (unsigned short*)(ws + 5 * NX * 2 + 2 * NW * 2);
  unsigned short* wob = (unsigned short*)(ws + 5 * NX * 2 + 3 * NW * 2);

  castk<<<(int)(NX / 1024), 256, 0, stream>>>(x, xb, (int)NX);
  castk<<<(int)(NW / 1024), 256, 0, stream>>>(Wq, wqb, (int)NW);
  castk<<<(int)(NW / 1024), 256, 0, stream>>>(Wk, wkb, (int)NW);
  castk<<<(int)(NW / 1024), 256, 0, stream>>>(Wv, wvb, (int)NW);
  castk<<<(int)(NW / 1024), 256, 0, stream>>>(Wo, wob, (int)NW);

  dim3 gg(8192 / BM, CC / BN);  // 64 x 8
  gemm_bt<0><<<gg, 256, 0, stream>>>(xb, wqb, qb, 8192, CC, CC);
  gemm_bt<0><<<gg, 256, 0, stream>>>(xb, wkb, kb, 8192, CC, CC);
  gemm_bt<0><<<gg, 256, 0, stream>>>(xb, wvb, vb, 8192, CC, CC);

  attn<<<dim3(16, 4 * HH), 256, 0, stream>>>(qb, kb, vb, ob);

  gemm_bt<1><<<gg, 256, 0, stream>>>(ob, wob, d_out, 8192, CC, CC);
}

// Round 11
// 367.697 us; speedup vs baseline: 1.8719x; 1.8719x over previous
//
#include <hip/hip_runtime.h>

// Problem constants: B=4, T=2048, C=1024, H=16, HD=64
#define TT 2048
#define CC 1024
#define HH 16
#define HD 64

typedef __bf16 bf16x8 __attribute__((ext_vector_type(8)));
typedef float f32x4 __attribute__((ext_vector_type(4)));

using as1_cvoid = __attribute__((address_space(1))) const void;
using as3_void  = __attribute__((address_space(3))) void;

__device__ __forceinline__ unsigned short f2bf(float f) {
  __bf16 b = (__bf16)f;
  return __builtin_bit_cast(unsigned short, b);
}

__device__ __forceinline__ void gload_lds16(const void* g, void* l) {
  __builtin_amdgcn_global_load_lds((as1_cvoid*)g, (as3_void*)l, 16, 0, 0);
}

// ---------------- cast f32 -> bf16 ----------------
__global__ void castk(const float* __restrict__ s, unsigned short* __restrict__ d, int n) {
  int i = (blockIdx.x * blockDim.x + threadIdx.x) * 4;
  if (i < n) {
    float4 v = *reinterpret_cast<const float4*>(s + i);
    ushort4 o;
    o.x = f2bf(v.x); o.y = f2bf(v.y); o.z = f2bf(v.z); o.w = f2bf(v.w);
    *reinterpret_cast<ushort4*>(d + i) = o;
  }
}

// ---------------- GEMM: C[M,N] = A[M,K] @ B[N,K]^T (verified) ----------------
#define BM 128
#define BN 128
#define BK 64

__device__ __forceinline__ void stage128x64(const unsigned short* __restrict__ src,
                                            int ld, char* ldsbase, int tid) {
#pragma unroll
  for (int it = 0; it < 4; ++it) {
    int j = it * 256 + tid;          // 16B block index, 1024 total
    int row = j >> 3;                // 8 blocks per 128B row
    int lg = (j & 7) ^ (row & 7);    // swizzled k-group (pre-swizzle SOURCE)
    const unsigned short* g = src + row * ld + lg * 8;
    gload_lds16(g, ldsbase + j * 16);
  }
}

template <int OUTF32>
__global__ __launch_bounds__(256)
void gemm_bt(const unsigned short* __restrict__ A, const unsigned short* __restrict__ B,
             void* __restrict__ Cout, int M, int N, int K) {
  __shared__ char lds[2][2 * BM * BK * 2];  // [buf][A 16KB | B 16KB]
  const int tid = threadIdx.x;
  const int lane = tid & 63;
  const int w = tid >> 6;
  const int wr = w >> 1, wc = w & 1;
  const int l15 = lane & 15, l4 = lane >> 4;

  const int rowA0 = blockIdx.x * BM;
  const int colB0 = blockIdx.y * BN;

  f32x4 acc[4][4] = {};

  const unsigned short* Abase = A + (size_t)rowA0 * K;
  const unsigned short* Bbase = B + (size_t)colB0 * K;

  int a_off[2][4], b_off[2][4];
#pragma unroll
  for (int kk = 0; kk < 2; ++kk)
#pragma unroll
    for (int m = 0; m < 4; ++m) {
      int row = wr * 64 + m * 16 + l15;
      int g = kk * 4 + l4;
      a_off[kk][m] = row * 128 + ((g ^ (row & 7)) * 16);
      int rowb = wc * 64 + m * 16 + l15;
      b_off[kk][m] = rowb * 128 + ((g ^ (rowb & 7)) * 16);
    }

  const int NT = K / BK;
  stage128x64(Abase, K, &lds[0][0], tid);
  stage128x64(Bbase, K, &lds[0][BM * BK * 2], tid);
  asm volatile("s_waitcnt vmcnt(0)" ::: "memory");
  __syncthreads();

  int buf = 0;
  for (int t = 0; t < NT; ++t) {
    if (t + 1 < NT) {
      stage128x64(Abase + (t + 1) * BK, K, &lds[buf ^ 1][0], tid);
      stage128x64(Bbase + (t + 1) * BK, K, &lds[buf ^ 1][BM * BK * 2], tid);
    }
    const char* aLds = &lds[buf][0];
    const char* bLds = &lds[buf][BM * BK * 2];
#pragma unroll
    for (int kk = 0; kk < 2; ++kk) {
      bf16x8 af[4], bfv[4];
#pragma unroll
      for (int m = 0; m < 4; ++m) af[m] = *reinterpret_cast<const bf16x8*>(aLds + a_off[kk][m]);
#pragma unroll
      for (int n = 0; n < 4; ++n) bfv[n] = *reinterpret_cast<const bf16x8*>(bLds + b_off[kk][n]);
#pragma unroll
      for (int m = 0; m < 4; ++m)
#pragma unroll
        for (int n = 0; n < 4; ++n)
          acc[m][n] = __builtin_amdgcn_mfma_f32_16x16x32_bf16(af[m], bfv[n], acc[m][n], 0, 0, 0);
    }
    asm volatile("s_waitcnt vmcnt(0)" ::: "memory");
    __syncthreads();
    buf ^= 1;
  }

#pragma unroll
  for (int m = 0; m < 4; ++m) {
#pragma unroll
    for (int r = 0; r < 4; ++r) {
      int row = rowA0 + wr * 64 + m * 16 + l4 * 4 + r;
#pragma unroll
      for (int n = 0; n < 4; ++n) {
        int col = colB0 + wc * 64 + n * 16 + l15;
        if (OUTF32)
          reinterpret_cast<float*>(Cout)[(size_t)row * N + col] = acc[m][n][r];
        else
          reinterpret_cast<unsigned short*>(Cout)[(size_t)row * N + col] = f2bf(acc[m][n][r]);
      }
    }
  }
}

// ---------------- causal flash attention ----------------
// Round-10 pipelined structure (verified PASS), with the spill-inducing
// __launch_bounds__(256,4) reverted to plain (256): round-10's ",4" made the
// backend clamp to 64 VGPR -> 800MB/dispatch scratch traffic (FETCH 862MB,
// WRITE 80MB). Structure kept:
//  - K double-buffered in LDS; K(t+1) gload + V(t+1) reg-load issued BEFORE
//    compute(t); vmcnt(0) after compute -> staging latency hidden.
//  - log2-space softmax (sc2 = sc*log2e, m in log2 units).
__global__ __launch_bounds__(256)
void attn(const unsigned short* __restrict__ Q, const unsigned short* __restrict__ Kmat,
          const unsigned short* __restrict__ V, unsigned short* __restrict__ O) {
  __shared__ char smem[32768];  // Ks0 8KB | Ks1 8KB | VsL 8KB | Pw 4x2KB
  const int tid = threadIdx.x, lane = tid & 63, w = tid >> 6;
  const int l15 = lane & 15, l4 = lane >> 4;
  const int i = blockIdx.x;             // [0, 16): pair index
  const int bh = blockIdx.y;
  const int b = bh >> 4, h = bh & 15;
  const size_t bT = (size_t)b * TT;
  const int q0A = i * 64 + w * 16;          // group A: qblock i
  const int q0B = (31 - i) * 64 + w * 16;   // group B: qblock 31-i
  const int lastA = i;                      // A's diagonal tile
  const int lastB = 31 - i;                 // B's diagonal tile (= loop bound)

  char* VsL = smem + 16384;
  char* Pw = smem + 24576 + w * 2048;

  // Q fragments (A-operand): row = l15, k = kk*32 + l4*8 + j
  const unsigned short* qpA = Q + (bT + q0A + l15) * CC + h * HD;
  const unsigned short* qpB = Q + (bT + q0B + l15) * CC + h * HD;
  bf16x8 qfA[2], qfB[2];
  qfA[0] = *reinterpret_cast<const bf16x8*>(qpA + l4 * 8);
  qfA[1] = *reinterpret_cast<const bf16x8*>(qpA + 32 + l4 * 8);
  qfB[0] = *reinterpret_cast<const bf16x8*>(qpB + l4 * 8);
  qfB[1] = *reinterpret_cast<const bf16x8*>(qpB + 32 + l4 * 8);

  f32x4 oA[4] = {}, oB[4] = {};
  float mA[4], lA[4], mB[4], lB[4];
#pragma unroll
  for (int r = 0; r < 4; ++r) {
    mA[r] = -1e30f; lA[r] = 0.f; mB[r] = -1e30f; lB[r] = 0.f;
  }

  int koff[4][2], voff[4][2], poff[2];
#pragma unroll
  for (int n = 0; n < 4; ++n)
#pragma unroll
    for (int kk = 0; kk < 2; ++kk) {
      int row = n * 16 + l15;
      int g = kk * 4 + l4;
      koff[n][kk] = row * 128 + ((g ^ (row & 7)) * 16);
      voff[n][kk] = row * 128 + ((g ^ (row & 7) ^ ((row >> 3) & 7)) * 16);
    }
#pragma unroll
  for (int kk = 0; kk < 2; ++kk) {
    int row = l15;
    int g = kk * 4 + l4;
    poff[kk] = row * 128 + ((g ^ (row & 7)) * 16);
  }

  const float sc2 = 0.125f * 1.44269504f;  // HD^-0.5 * log2(e); m in log2 units
  bf16x8 vreg[2];

  // stage K(t) gload into dst; load V(t) into vreg
#define STAGE_K(KB0, DST)                                                        \
  _Pragma("unroll")                                                              \
  for (int it = 0; it < 2; ++it) {                                               \
    int j = it * 256 + tid;                                                      \
    int row = j >> 3;                                                            \
    int lg = (j & 7) ^ (row & 7);                                                \
    gload_lds16(Kmat + (bT + (KB0) + row) * CC + h * HD + lg * 8, (DST) + j * 16); \
  }
#define LOAD_V(KB0)                                                              \
  _Pragma("unroll")                                                              \
  for (int it = 0; it < 2; ++it) {                                               \
    int j = it * 256 + tid;                                                      \
    int key = j >> 3;                                                            \
    int d0 = (j & 7) * 8;                                                        \
    vreg[it] = *reinterpret_cast<const bf16x8*>(V + (bT + (KB0) + key) * CC + h * HD + d0); \
  }
#define WRITE_V()                                                                \
  _Pragma("unroll")                                                              \
  for (int it = 0; it < 2; ++it) {                                               \
    int j = it * 256 + tid;                                                      \
    int key = j >> 3;                                                            \
    int d0 = (j & 7) * 8;                                                        \
    _Pragma("unroll")                                                            \
    for (int jj = 0; jj < 8; ++jj) {                                             \
      int row = d0 + jj;                                                         \
      int gq = key >> 3;                                                         \
      int off = row * 128 + ((gq ^ (row & 7) ^ ((row >> 3) & 7)) * 16) + (key & 7) * 2; \
      *reinterpret_cast<__bf16*>(VsL + off) = vreg[it][jj];                      \
    }                                                                            \
  }

  // verified per-tile body (round-9 math, log2-space softmax)
#define TILE_BODY(QF, OO, MR, LR, Q0, ISDIAG, KB0)                               \
  {                                                                              \
    f32x4 s_[4] = {};                                                            \
    _Pragma("unroll")                                                            \
    for (int n = 0; n < 4; ++n)                                                  \
      _Pragma("unroll")                                                          \
      for (int kk = 0; kk < 2; ++kk) {                                           \
        bf16x8 kf = *reinterpret_cast<const bf16x8*>(Ks + koff[n][kk]);          \
        s_[n] = __builtin_amdgcn_mfma_f32_16x16x32_bf16(QF[kk], kf, s_[n], 0, 0, 0); \
      }                                                                          \
    if (ISDIAG) {                                                                \
      _Pragma("unroll")                                                          \
      for (int n = 0; n < 4; ++n) {                                              \
        int key = (KB0) + n * 16 + l15;                                          \
        _Pragma("unroll")                                                        \
        for (int r = 0; r < 4; ++r) {                                            \
          int q = (Q0) + l4 * 4 + r;                                             \
          if (key > q) s_[n][r] = -1e30f;                                        \
        }                                                                        \
      }                                                                          \
    }                                                                            \
    float tm_[4];                                                                \
    _Pragma("unroll")                                                            \
    for (int r = 0; r < 4; ++r)                                                  \
      tm_[r] = fmaxf(fmaxf(s_[0][r], s_[1][r]), fmaxf(s_[2][r], s_[3][r]));      \
    _Pragma("unroll")                                                            \
    for (int off = 1; off < 16; off <<= 1)                                       \
      _Pragma("unroll")                                                          \
      for (int r = 0; r < 4; ++r) tm_[r] = fmaxf(tm_[r], __shfl_xor(tm_[r], off, 64)); \
    float mnew_[4], alpha_[4];                                                   \
    _Pragma("unroll")                                                            \
    for (int r = 0; r < 4; ++r) {                                                \
      mnew_[r] = fmaxf(MR[r], tm_[r] * sc2);                                     \
      alpha_[r] = exp2f(MR[r] - mnew_[r]);                                       \
      MR[r] = mnew_[r];                                                          \
    }                                                                            \
    float ts_[4] = {0.f, 0.f, 0.f, 0.f};                                         \
    _Pragma("unroll")                                                            \
    for (int n = 0; n < 4; ++n)                                                  \
      _Pragma("unroll")                                                          \
      for (int r = 0; r < 4; ++r) {                                              \
        float p = exp2f(s_[n][r] * sc2 - mnew_[r]);                              \
        s_[n][r] = p;                                                            \
        ts_[r] += p;                                                             \
      }                                                                          \
    _Pragma("unroll")                                                            \
    for (int off = 1; off < 16; off <<= 1)                                       \
      _Pragma("unroll")                                                          \
      for (int r = 0; r < 4; ++r) ts_[r] += __shfl_xor(ts_[r], off, 64);         \
    _Pragma("unroll")                                                            \
    for (int r = 0; r < 4; ++r) LR[r] = LR[r] * alpha_[r] + ts_[r];              \
    _Pragma("unroll")                                                            \
    for (int nf2 = 0; nf2 < 4; ++nf2)                                            \
      _Pragma("unroll")                                                          \
      for (int r = 0; r < 4; ++r) OO[nf2][r] *= alpha_[r];                       \
    _Pragma("unroll")                                                            \
    for (int n = 0; n < 4; ++n)                                                  \
      _Pragma("unroll")                                                          \
      for (int r = 0; r < 4; ++r) {                                              \
        int row = l4 * 4 + r;                                                    \
        int col = n * 16 + l15;                                                  \
        int gq = col >> 3;                                                       \
        int off = row * 128 + ((gq ^ (row & 7)) * 16) + (col & 7) * 2;           \
        *reinterpret_cast<__bf16*>(Pw + off) = (__bf16)s_[n][r];                 \
      }                                                                          \
    asm volatile("s_waitcnt lgkmcnt(0)" ::: "memory");                           \
    __builtin_amdgcn_sched_barrier(0);                                           \
    _Pragma("unroll")                                                            \
    for (int kk = 0; kk < 2; ++kk) {                                             \
      bf16x8 pf = *reinterpret_cast<const bf16x8*>(Pw + poff[kk]);               \
      _Pragma("unroll")                                                          \
      for (int nf2 = 0; nf2 < 4; ++nf2) {                                        \
        bf16x8 vf = *reinterpret_cast<const bf16x8*>(VsL + voff[nf2][kk]);       \
        OO[nf2] = __builtin_amdgcn_mfma_f32_16x16x32_bf16(pf, vf, OO[nf2], 0, 0, 0); \
      }                                                                          \
    }                                                                            \
  }

  // prologue: stage tile 0 (K -> Ks0, V -> regs -> VsL)
  STAGE_K(0, smem)
  LOAD_V(0)
  asm volatile("s_waitcnt vmcnt(0)" ::: "memory");
  WRITE_V()
  __syncthreads();

  int buf = 0;
  for (int t = 0; t <= lastB; ++t) {
    const int kb0 = t * 64;
    // issue next tile's loads BEFORE compute: K(t+1) -> Ks[buf^1] (dead region),
    // V(t+1) -> vreg (free). Latency hides under the tile body.
    if (t < lastB) {
      char* kDst = smem + (buf ^ 1) * 8192;
      STAGE_K(kb0 + 64, kDst)
      LOAD_V(kb0 + 64)
    }
    const char* Ks = smem + buf * 8192;

    if (t <= lastA) {  // wave-uniform guard
      TILE_BODY(qfA, oA, mA, lA, q0A, (t == lastA), kb0)
    }
    TILE_BODY(qfB, oB, mB, lB, q0B, (t == lastB), kb0)

    __syncthreads();  // all waves done reading VsL / Ks[buf] / Pw
    if (t < lastB) {
      asm volatile("s_waitcnt vmcnt(0)" ::: "memory");  // K(t+1), V(t+1) landed
      WRITE_V()
      __syncthreads();  // V(t+1) visible; K(t+1) in Ks[buf^1]
    }
    buf ^= 1;
  }
#undef TILE_BODY
#undef STAGE_K
#undef LOAD_V
#undef WRITE_V

  // epilogue: O[b,q, h*64+d] bf16, both groups
#pragma unroll
  for (int nf2 = 0; nf2 < 4; ++nf2)
#pragma unroll
    for (int r = 0; r < 4; ++r) {
      int col = h * HD + nf2 * 16 + l15;
      int qA = q0A + l4 * 4 + r;
      O[(bT + qA) * CC + col] = f2bf(oA[nf2][r] / lA[r]);
      int qB = q0B + l4 * 4 + r;
      O[(bT + qB) * CC + col] = f2bf(oB[nf2][r] / lB[r]);
    }
}

// ---------------- launch ----------------
extern "C" void kernel_launch(void* const* d_in, const int* in_sizes, int n_in,
                              void* d_out, int out_size, void* d_ws, size_t ws_size,
                              hipStream_t stream) {
  const float* x  = (const float*)d_in[0];
  const float* Wq = (const float*)d_in[1];
  const float* Wk = (const float*)d_in[2];
  const float* Wv = (const float*)d_in[3];
  const float* Wo = (const float*)d_in[4];

  char* ws = (char*)d_ws;
  const size_t NX = (size_t)4 * TT * CC;       // 8388608
  const size_t NW = (size_t)CC * CC;           // 1048576
  unsigned short* xb  = (unsigned short*)(ws);
  unsigned short* qb  = (unsigned short*)(ws + 1 * NX * 2);
  unsigned short* kb  = (unsigned short*)(ws + 2 * NX * 2);
  unsigned short* vb  = (unsigned short*)(ws + 3 * NX * 2);
  unsigned short* ob  = (unsigned short*)(ws + 4 * NX * 2);
  unsigned short* wqb = (unsigned short*)(ws + 5 * NX * 2);
  unsigned short* wkb = (unsigned short*)(ws + 5 * NX * 2 + 1 * NW * 2);
  unsigned short* wvb = (unsigned short*)(ws + 5 * NX * 2 + 2 * NW * 2);
  unsigned short* wob = (unsigned short*)(ws + 5 * NX * 2 + 3 * NW * 2);

  castk<<<(int)(NX / 1024), 256, 0, stream>>>(x, xb, (int)NX);
  castk<<<(int)(NW / 1024), 256, 0, stream>>>(Wq, wqb, (int)NW);
  castk<<<(int)(NW / 1024), 256, 0, stream>>>(Wk, wkb, (int)NW);
  castk<<<(int)(NW / 1024), 256, 0, stream>>>(Wv, wvb, (int)NW);
  castk<<<(int)(NW / 1024), 256, 0, stream>>>(Wo, wob, (int)NW);

  dim3 gg(8192 / BM, CC / BN);  // 64 x 8
  gemm_bt<0><<<gg, 256, 0, stream>>>(xb, wqb, qb, 8192, CC, CC);
  gemm_bt<0><<<gg, 256, 0, stream>>>(xb, wkb, kb, 8192, CC, CC);
  gemm_bt<0><<<gg, 256, 0, stream>>>(xb, wvb, vb, 8192, CC, CC);

  attn<<<dim3(16, 4 * HH), 256, 0, stream>>>(qb, kb, vb, ob);

  gemm_bt<1><<<gg, 256, 0, stream>>>(ob, wob, d_out, 8192, CC, CC);
}